// Round 1
// baseline (1026.593 us; speedup 1.0000x reference)
//
#include <hip/hip_runtime.h>

// Problem constants (fixed shapes from the reference):
//   feat0: [1, 32, 128, 128, 32]   (D=128, H=128, W=32)
//   feat1: [1, 32, 128, 32, 128]   (D=128, H=32,  W=128)
//   feat2: [1, 32, 32, 128, 128]   (D=32,  H=128, W=128)
//   verts_i: [1, *, *, *, 3] -> P = 524288 points each
// out: [3, 1, 32, P] float32

#define WS_P 524288          // points per grid == D*H*W for every feat
#define NCH 32               // channels

// ---- ordered-uint encoding for float atomic min/max (exact, order-independent)
__device__ __forceinline__ unsigned encf(float f) {
    unsigned b = __float_as_uint(f);
    return (b & 0x80000000u) ? ~b : (b | 0x80000000u);
}
__device__ __forceinline__ float decf(unsigned u) {
    unsigned b = (u & 0x80000000u) ? (u & 0x7FFFFFFFu) : ~u;
    return __uint_as_float(b);
}

__global__ void init_mm_kernel(unsigned* mm) {
    int t = threadIdx.x;
    // layout: mm[g*6 + k*2 + 0] = min (encoded), +1 = max (encoded)
    if (t < 18) mm[t] = (t & 1) ? 0u : 0xFFFFFFFFu;
}

__global__ __launch_bounds__(256) void minmax_kernel(
    const float* __restrict__ v0, const float* __restrict__ v1,
    const float* __restrict__ v2, unsigned* __restrict__ mm)
{
    const int g = blockIdx.y;
    const float* v = (g == 0) ? v0 : (g == 1) ? v1 : v2;
    const int tid = threadIdx.x;

    float mn[3] = { INFINITY, INFINITY, INFINITY };
    float mx[3] = { -INFINITY, -INFINITY, -INFINITY };

    for (int idx = blockIdx.x * 256 + tid; idx < WS_P; idx += 128 * 256) {
        #pragma unroll
        for (int k = 0; k < 3; k++) {
            float f = v[(size_t)idx * 3 + k];
            mn[k] = fminf(mn[k], f);
            mx[k] = fmaxf(mx[k], f);
        }
    }

    __shared__ float smn[3][256];
    __shared__ float smx[3][256];
    #pragma unroll
    for (int k = 0; k < 3; k++) { smn[k][tid] = mn[k]; smx[k][tid] = mx[k]; }
    __syncthreads();

    for (int s = 128; s > 0; s >>= 1) {
        if (tid < s) {
            #pragma unroll
            for (int k = 0; k < 3; k++) {
                smn[k][tid] = fminf(smn[k][tid], smn[k][tid + s]);
                smx[k][tid] = fmaxf(smx[k][tid], smx[k][tid + s]);
            }
        }
        __syncthreads();
    }

    if (tid == 0) {
        #pragma unroll
        for (int k = 0; k < 3; k++) {
            atomicMin(&mm[g * 6 + k * 2 + 0], encf(smn[k][0]));
            atomicMax(&mm[g * 6 + k * 2 + 1], encf(smx[k][0]));
        }
    }
}

// [C][N] -> [N][C] transpose (N = WS_P), 32x32 tiles via LDS. blockIdx.y selects feat.
__global__ __launch_bounds__(256) void transpose_kernel(
    const float* __restrict__ f0, const float* __restrict__ f1,
    const float* __restrict__ f2,
    float* __restrict__ t0, float* __restrict__ t1, float* __restrict__ t2)
{
    const int j = blockIdx.y;
    const float* in = (j == 0) ? f0 : (j == 1) ? f1 : f2;
    float* out = (j == 0) ? t0 : (j == 1) ? t1 : t2;

    __shared__ float tile[32][33];
    const int tx = threadIdx.x;   // 0..31
    const int ty = threadIdx.y;   // 0..7
    const int n0 = blockIdx.x * 32;

    #pragma unroll
    for (int r = 0; r < 4; r++) {
        int c = ty + r * 8;
        tile[c][tx] = in[(size_t)c * WS_P + n0 + tx];
    }
    __syncthreads();
    #pragma unroll
    for (int r = 0; r < 4; r++) {
        int pl = ty + r * 8;
        out[(size_t)(n0 + pl) * NCH + tx] = tile[tx][pl];
    }
}

// One thread per point. I = which grid (compile-time => dims/pointers constant-folded).
// TR: sample from transposed [N][32] layout (float4 x8 per corner) vs fallback scalar.
template<int I, bool TR>
__global__ __launch_bounds__(256) void sample_kernel(
    const float* __restrict__ f0, const float* __restrict__ f1,
    const float* __restrict__ f2,
    const float* __restrict__ t0, const float* __restrict__ t1,
    const float* __restrict__ t2,
    const float* __restrict__ v0, const float* __restrict__ v1,
    const float* __restrict__ v2,
    const unsigned* __restrict__ mm, float* __restrict__ out)
{
    constexpr int Dd[3] = { 128, 128, 32 };
    constexpr int Hh[3] = { 128, 32, 128 };
    constexpr int Ww[3] = { 32, 128, 128 };

    const int p = blockIdx.x * 256 + threadIdx.x;

    const float* verts = (I == 0) ? v0 : (I == 1) ? v1 : v2;
    const float* fi    = (I == 0) ? f0 : (I == 1) ? f1 : f2;

    // normalized grid coords g[k] in [-1,1] exactly as reference:
    // g = (v - mn)/(mx - mn)*2 - 1
    float g[3];
    #pragma unroll
    for (int k = 0; k < 3; k++) {
        float mn = decf(mm[I * 6 + k * 2 + 0]);
        float mx = decf(mm[I * 6 + k * 2 + 1]);
        float vv = verts[(size_t)p * 3 + k];
        g[k] = (vv - mn) / (mx - mn) * 2.0f - 1.0f;
    }

    // accumulator initialized with feat_i (coalesced: lanes vary p, stride-P per channel)
    float acc[NCH];
    #pragma unroll
    for (int c = 0; c < NCH; c++) acc[c] = fi[(size_t)c * WS_P + p];

    #pragma unroll
    for (int jj = 0; jj < 2; jj++) {
        const int j = (I + 1 + jj) % 3;   // unrolled => compile-time
        const float* src = TR ? ((j == 0) ? t0 : (j == 1) ? t1 : t2)
                              : ((j == 0) ? f0 : (j == 1) ? f1 : f2);
        const int W = Ww[j], H = Hh[j], D = Dd[j];

        // torch convention: grid ch0 -> W (x), ch1 -> H (y), ch2 -> D (z)
        float ix = (g[0] + 1.0f) * 0.5f * (float)(W - 1);
        float iy = (g[1] + 1.0f) * 0.5f * (float)(H - 1);
        float iz = (g[2] + 1.0f) * 0.5f * (float)(D - 1);
        float fx = floorf(ix), fy = floorf(iy), fz = floorf(iz);
        float wx = ix - fx, wy = iy - fy, wz = iz - fz;

        int x0 = (int)fx; x0 = x0 < 0 ? 0 : (x0 > W - 1 ? W - 1 : x0);
        int y0 = (int)fy; y0 = y0 < 0 ? 0 : (y0 > H - 1 ? H - 1 : y0);
        int z0 = (int)fz; z0 = z0 < 0 ? 0 : (z0 > D - 1 ? D - 1 : z0);
        int x1 = (x0 + 1 > W - 1) ? W - 1 : x0 + 1;
        int y1 = (y0 + 1 > H - 1) ? H - 1 : y0 + 1;
        int z1 = (z0 + 1 > D - 1) ? D - 1 : z0 + 1;

        float ux = 1.0f - wx, uy = 1.0f - wy, uz = 1.0f - wz;
        float w[8] = { uz * uy * ux, uz * uy * wx, uz * wy * ux, uz * wy * wx,
                       wz * uy * ux, wz * uy * wx, wz * wy * ux, wz * wy * wx };

        int r00 = (z0 * H + y0) * W;
        int r01 = (z0 * H + y1) * W;
        int r10 = (z1 * H + y0) * W;
        int r11 = (z1 * H + y1) * W;
        int o[8] = { r00 + x0, r00 + x1, r01 + x0, r01 + x1,
                     r10 + x0, r10 + x1, r11 + x0, r11 + x1 };

        if (TR) {
            #pragma unroll
            for (int cn = 0; cn < 8; cn++) {
                const float4* p4 =
                    reinterpret_cast<const float4*>(src + (size_t)o[cn] * NCH);
                float wt = w[cn];
                #pragma unroll
                for (int cg = 0; cg < 8; cg++) {
                    float4 f = p4[cg];
                    acc[cg * 4 + 0] = fmaf(wt, f.x, acc[cg * 4 + 0]);
                    acc[cg * 4 + 1] = fmaf(wt, f.y, acc[cg * 4 + 1]);
                    acc[cg * 4 + 2] = fmaf(wt, f.z, acc[cg * 4 + 2]);
                    acc[cg * 4 + 3] = fmaf(wt, f.w, acc[cg * 4 + 3]);
                }
            }
        } else {
            #pragma unroll
            for (int cn = 0; cn < 8; cn++) {
                float wt = w[cn];
                const float* sp = src + o[cn];
                #pragma unroll
                for (int c = 0; c < NCH; c++)
                    acc[c] = fmaf(wt, sp[(size_t)c * WS_P], acc[c]);
            }
        }
    }

    // out[I*C*P + c*P + p] — coalesced stores (lanes vary p)
    float* op = out + (size_t)I * NCH * WS_P + p;
    #pragma unroll
    for (int c = 0; c < NCH; c++) op[(size_t)c * WS_P] = acc[c];
}

extern "C" void kernel_launch(void* const* d_in, const int* in_sizes, int n_in,
                              void* d_out, int out_size, void* d_ws, size_t ws_size,
                              hipStream_t stream) {
    const float* f0 = (const float*)d_in[0];
    const float* f1 = (const float*)d_in[1];
    const float* f2 = (const float*)d_in[2];
    const float* v0 = (const float*)d_in[3];
    const float* v1 = (const float*)d_in[4];
    const float* v2 = (const float*)d_in[5];
    float* out = (float*)d_out;

    unsigned* mm = (unsigned*)d_ws;
    const size_t FEAT_ELEMS = (size_t)NCH * WS_P;   // 16,777,216 floats = 64 MB
    float* t0 = (float*)((char*)d_ws + 256);
    float* t1 = t0 + FEAT_ELEMS;
    float* t2 = t1 + FEAT_ELEMS;
    const bool tr = ws_size >= 256 + 3 * FEAT_ELEMS * sizeof(float);

    hipLaunchKernelGGL(init_mm_kernel, dim3(1), dim3(32), 0, stream, mm);
    hipLaunchKernelGGL(minmax_kernel, dim3(128, 3), dim3(256), 0, stream,
                       v0, v1, v2, mm);

    if (tr) {
        hipLaunchKernelGGL(transpose_kernel, dim3(WS_P / 32, 3), dim3(32, 8), 0,
                           stream, f0, f1, f2, t0, t1, t2);
        hipLaunchKernelGGL((sample_kernel<0, true>), dim3(WS_P / 256), dim3(256), 0,
                           stream, f0, f1, f2, t0, t1, t2, v0, v1, v2, mm, out);
        hipLaunchKernelGGL((sample_kernel<1, true>), dim3(WS_P / 256), dim3(256), 0,
                           stream, f0, f1, f2, t0, t1, t2, v0, v1, v2, mm, out);
        hipLaunchKernelGGL((sample_kernel<2, true>), dim3(WS_P / 256), dim3(256), 0,
                           stream, f0, f1, f2, t0, t1, t2, v0, v1, v2, mm, out);
    } else {
        hipLaunchKernelGGL((sample_kernel<0, false>), dim3(WS_P / 256), dim3(256), 0,
                           stream, f0, f1, f2, t0, t1, t2, v0, v1, v2, mm, out);
        hipLaunchKernelGGL((sample_kernel<1, false>), dim3(WS_P / 256), dim3(256), 0,
                           stream, f0, f1, f2, t0, t1, t2, v0, v1, v2, mm, out);
        hipLaunchKernelGGL((sample_kernel<2, false>), dim3(WS_P / 256), dim3(256), 0,
                           stream, f0, f1, f2, t0, t1, t2, v0, v1, v2, mm, out);
    }
}

// Round 2
// 628.483 us; speedup vs baseline: 1.6334x; 1.6334x over previous
//
#include <hip/hip_runtime.h>

// Shapes: feat0 [32,128,128,32], feat1 [32,128,32,128], feat2 [32,32,128,128]
// P = 524288 points per grid; out [3,32,P] fp32.

#define WS_P 524288
#define NCH 32

// ---- ordered-uint encoding for float atomic min/max (exact, order-independent)
__device__ __forceinline__ unsigned encf(float f) {
    unsigned b = __float_as_uint(f);
    return (b & 0x80000000u) ? ~b : (b | 0x80000000u);
}
__device__ __forceinline__ float decf(unsigned u) {
    unsigned b = (u & 0x80000000u) ? (u & 0x7FFFFFFFu) : ~u;
    return __uint_as_float(b);
}

__global__ void init_mm_kernel(unsigned* mm) {
    int t = threadIdx.x;
    if (t < 18) mm[t] = (t & 1) ? 0u : 0xFFFFFFFFu;
}

__global__ __launch_bounds__(256) void minmax_kernel(
    const float* __restrict__ v0, const float* __restrict__ v1,
    const float* __restrict__ v2, unsigned* __restrict__ mm)
{
    const int g = blockIdx.y;
    const float* v = (g == 0) ? v0 : (g == 1) ? v1 : v2;
    const int tid = threadIdx.x;

    float mn[3] = { INFINITY, INFINITY, INFINITY };
    float mx[3] = { -INFINITY, -INFINITY, -INFINITY };

    for (int idx = blockIdx.x * 256 + tid; idx < WS_P; idx += 128 * 256) {
        #pragma unroll
        for (int k = 0; k < 3; k++) {
            float f = v[(size_t)idx * 3 + k];
            mn[k] = fminf(mn[k], f);
            mx[k] = fmaxf(mx[k], f);
        }
    }

    __shared__ float smn[3][256];
    __shared__ float smx[3][256];
    #pragma unroll
    for (int k = 0; k < 3; k++) { smn[k][tid] = mn[k]; smx[k][tid] = mx[k]; }
    __syncthreads();

    for (int s = 128; s > 0; s >>= 1) {
        if (tid < s) {
            #pragma unroll
            for (int k = 0; k < 3; k++) {
                smn[k][tid] = fminf(smn[k][tid], smn[k][tid + s]);
                smx[k][tid] = fmaxf(smx[k][tid], smx[k][tid + s]);
            }
        }
        __syncthreads();
    }

    if (tid == 0) {
        #pragma unroll
        for (int k = 0; k < 3; k++) {
            atomicMin(&mm[g * 6 + k * 2 + 0], encf(smn[k][0]));
            atomicMax(&mm[g * 6 + k * 2 + 1], encf(smx[k][0]));
        }
    }
}

// [C][N] -> [N][C] transpose, 32x32 tiles via LDS. blockIdx.y selects feat.
__global__ __launch_bounds__(256) void transpose_kernel(
    const float* __restrict__ f0, const float* __restrict__ f1,
    const float* __restrict__ f2,
    float* __restrict__ t0, float* __restrict__ t1, float* __restrict__ t2)
{
    const int j = blockIdx.y;
    const float* in = (j == 0) ? f0 : (j == 1) ? f1 : f2;
    float* out = (j == 0) ? t0 : (j == 1) ? t1 : t2;

    __shared__ float tile[32][33];
    const int tx = threadIdx.x;   // 0..31
    const int ty = threadIdx.y;   // 0..7
    const int n0 = blockIdx.x * 32;

    #pragma unroll
    for (int r = 0; r < 4; r++) {
        int c = ty + r * 8;
        tile[c][tx] = in[(size_t)c * WS_P + n0 + tx];
    }
    __syncthreads();
    #pragma unroll
    for (int r = 0; r < 4; r++) {
        int pl = ty + r * 8;
        out[(size_t)(n0 + pl) * NCH + tx] = tile[tx][pl];
    }
}

// 8 lanes per point; each lane owns 4 channels (one float4 of the 128 B
// channel row). acc = 4 VGPRs -> high occupancy, ~17 loads/thread in flight.
template<int I>
__global__ __launch_bounds__(256, 8) void sample8_kernel(
    const float* __restrict__ t0, const float* __restrict__ t1,
    const float* __restrict__ t2,
    const float* __restrict__ v0, const float* __restrict__ v1,
    const float* __restrict__ v2,
    const unsigned* __restrict__ mm, float* __restrict__ out)
{
    constexpr int Dd[3] = { 128, 128, 32 };
    constexpr int Hh[3] = { 128, 32, 128 };
    constexpr int Ww[3] = { 32, 128, 128 };

    const int tid = threadIdx.x;
    const int p = blockIdx.x * 32 + (tid >> 3);   // point index
    const int subp = tid & 7;                     // which float4 of 32 channels

    const float* verts = (I == 0) ? v0 : (I == 1) ? v1 : v2;
    const float* ti    = (I == 0) ? t0 : (I == 1) ? t1 : t2;

    float g[3];
    #pragma unroll
    for (int k = 0; k < 3; k++) {
        float mn = decf(mm[I * 6 + k * 2 + 0]);
        float mx = decf(mm[I * 6 + k * 2 + 1]);
        float vv = verts[(size_t)p * 3 + k];
        g[k] = (vv - mn) / (mx - mn) * 2.0f - 1.0f;
    }

    // init accumulator from transposed feat_i (coalesced float4)
    float4 acc = reinterpret_cast<const float4*>(ti)[(size_t)p * 8 + subp];

    #pragma unroll
    for (int jj = 0; jj < 2; jj++) {
        const int j = (I + 1 + jj) % 3;   // compile-time after unroll
        const float* src = (j == 0) ? t0 : (j == 1) ? t1 : t2;
        const int W = Ww[j], H = Hh[j], D = Dd[j];

        float ix = (g[0] + 1.0f) * 0.5f * (float)(W - 1);
        float iy = (g[1] + 1.0f) * 0.5f * (float)(H - 1);
        float iz = (g[2] + 1.0f) * 0.5f * (float)(D - 1);
        float fx = floorf(ix), fy = floorf(iy), fz = floorf(iz);
        float wx = ix - fx, wy = iy - fy, wz = iz - fz;

        int x0 = (int)fx; x0 = x0 < 0 ? 0 : (x0 > W - 1 ? W - 1 : x0);
        int y0 = (int)fy; y0 = y0 < 0 ? 0 : (y0 > H - 1 ? H - 1 : y0);
        int z0 = (int)fz; z0 = z0 < 0 ? 0 : (z0 > D - 1 ? D - 1 : z0);
        int x1 = (x0 + 1 > W - 1) ? W - 1 : x0 + 1;
        int y1 = (y0 + 1 > H - 1) ? H - 1 : y0 + 1;
        int z1 = (z0 + 1 > D - 1) ? D - 1 : z0 + 1;

        float ux = 1.0f - wx, uy = 1.0f - wy, uz = 1.0f - wz;
        float w[8] = { uz * uy * ux, uz * uy * wx, uz * wy * ux, uz * wy * wx,
                       wz * uy * ux, wz * uy * wx, wz * wy * ux, wz * wy * wx };

        int r00 = (z0 * H + y0) * W;
        int r01 = (z0 * H + y1) * W;
        int r10 = (z1 * H + y0) * W;
        int r11 = (z1 * H + y1) * W;
        int o[8] = { r00 + x0, r00 + x1, r01 + x0, r01 + x1,
                     r10 + x0, r10 + x1, r11 + x0, r11 + x1 };

        const float4* s4 = reinterpret_cast<const float4*>(src);
        // two batches of 4 corners: 4 loads in flight, then 4 fma groups
        #pragma unroll
        for (int h = 0; h < 2; h++) {
            float4 fA = s4[(size_t)o[h * 4 + 0] * 8 + subp];
            float4 fB = s4[(size_t)o[h * 4 + 1] * 8 + subp];
            float4 fC = s4[(size_t)o[h * 4 + 2] * 8 + subp];
            float4 fD = s4[(size_t)o[h * 4 + 3] * 8 + subp];
            float wA = w[h * 4 + 0], wB = w[h * 4 + 1];
            float wC = w[h * 4 + 2], wD = w[h * 4 + 3];
            acc.x = fmaf(wA, fA.x, acc.x); acc.y = fmaf(wA, fA.y, acc.y);
            acc.z = fmaf(wA, fA.z, acc.z); acc.w = fmaf(wA, fA.w, acc.w);
            acc.x = fmaf(wB, fB.x, acc.x); acc.y = fmaf(wB, fB.y, acc.y);
            acc.z = fmaf(wB, fB.z, acc.z); acc.w = fmaf(wB, fB.w, acc.w);
            acc.x = fmaf(wC, fC.x, acc.x); acc.y = fmaf(wC, fC.y, acc.y);
            acc.z = fmaf(wC, fC.z, acc.z); acc.w = fmaf(wC, fC.w, acc.w);
            acc.x = fmaf(wD, fD.x, acc.x); acc.y = fmaf(wD, fD.y, acc.y);
            acc.z = fmaf(wD, fD.z, acc.z); acc.w = fmaf(wD, fD.w, acc.w);
        }
    }

    // transpose through LDS so [C][P] stores are 128 B coalesced
    __shared__ float sb[32][33];
    const int pl = tid >> 3;
    sb[pl][subp * 4 + 0] = acc.x;
    sb[pl][subp * 4 + 1] = acc.y;
    sb[pl][subp * 4 + 2] = acc.z;
    sb[pl][subp * 4 + 3] = acc.w;
    __syncthreads();

    const int p0 = blockIdx.x * 32;
    float* op = out + (size_t)I * NCH * WS_P;
    #pragma unroll
    for (int it = 0; it < 4; it++) {
        int c = it * 8 + (tid >> 5);
        op[(size_t)c * WS_P + p0 + (tid & 31)] = sb[tid & 31][c];
    }
}

// fallback (ws too small): original 1-thread-per-point scalar-gather path
template<int I>
__global__ __launch_bounds__(256) void sample_fallback_kernel(
    const float* __restrict__ f0, const float* __restrict__ f1,
    const float* __restrict__ f2,
    const float* __restrict__ v0, const float* __restrict__ v1,
    const float* __restrict__ v2,
    const unsigned* __restrict__ mm, float* __restrict__ out)
{
    constexpr int Dd[3] = { 128, 128, 32 };
    constexpr int Hh[3] = { 128, 32, 128 };
    constexpr int Ww[3] = { 32, 128, 128 };

    const int p = blockIdx.x * 256 + threadIdx.x;
    const float* verts = (I == 0) ? v0 : (I == 1) ? v1 : v2;
    const float* fi    = (I == 0) ? f0 : (I == 1) ? f1 : f2;

    float g[3];
    #pragma unroll
    for (int k = 0; k < 3; k++) {
        float mn = decf(mm[I * 6 + k * 2 + 0]);
        float mx = decf(mm[I * 6 + k * 2 + 1]);
        float vv = verts[(size_t)p * 3 + k];
        g[k] = (vv - mn) / (mx - mn) * 2.0f - 1.0f;
    }

    float acc[NCH];
    #pragma unroll
    for (int c = 0; c < NCH; c++) acc[c] = fi[(size_t)c * WS_P + p];

    #pragma unroll
    for (int jj = 0; jj < 2; jj++) {
        const int j = (I + 1 + jj) % 3;
        const float* src = (j == 0) ? f0 : (j == 1) ? f1 : f2;
        const int W = Ww[j], H = Hh[j], D = Dd[j];

        float ix = (g[0] + 1.0f) * 0.5f * (float)(W - 1);
        float iy = (g[1] + 1.0f) * 0.5f * (float)(H - 1);
        float iz = (g[2] + 1.0f) * 0.5f * (float)(D - 1);
        float fx = floorf(ix), fy = floorf(iy), fz = floorf(iz);
        float wx = ix - fx, wy = iy - fy, wz = iz - fz;

        int x0 = (int)fx; x0 = x0 < 0 ? 0 : (x0 > W - 1 ? W - 1 : x0);
        int y0 = (int)fy; y0 = y0 < 0 ? 0 : (y0 > H - 1 ? H - 1 : y0);
        int z0 = (int)fz; z0 = z0 < 0 ? 0 : (z0 > D - 1 ? D - 1 : z0);
        int x1 = (x0 + 1 > W - 1) ? W - 1 : x0 + 1;
        int y1 = (y0 + 1 > H - 1) ? H - 1 : y0 + 1;
        int z1 = (z0 + 1 > D - 1) ? D - 1 : z0 + 1;

        float ux = 1.0f - wx, uy = 1.0f - wy, uz = 1.0f - wz;
        float w[8] = { uz * uy * ux, uz * uy * wx, uz * wy * ux, uz * wy * wx,
                       wz * uy * ux, wz * uy * wx, wz * wy * ux, wz * wy * wx };

        int r00 = (z0 * H + y0) * W;
        int r01 = (z0 * H + y1) * W;
        int r10 = (z1 * H + y0) * W;
        int r11 = (z1 * H + y1) * W;
        int o[8] = { r00 + x0, r00 + x1, r01 + x0, r01 + x1,
                     r10 + x0, r10 + x1, r11 + x0, r11 + x1 };

        #pragma unroll
        for (int cn = 0; cn < 8; cn++) {
            float wt = w[cn];
            const float* sp = src + o[cn];
            #pragma unroll
            for (int c = 0; c < NCH; c++)
                acc[c] = fmaf(wt, sp[(size_t)c * WS_P], acc[c]);
        }
    }

    float* op = out + (size_t)I * NCH * WS_P + p;
    #pragma unroll
    for (int c = 0; c < NCH; c++) op[(size_t)c * WS_P] = acc[c];
}

extern "C" void kernel_launch(void* const* d_in, const int* in_sizes, int n_in,
                              void* d_out, int out_size, void* d_ws, size_t ws_size,
                              hipStream_t stream) {
    const float* f0 = (const float*)d_in[0];
    const float* f1 = (const float*)d_in[1];
    const float* f2 = (const float*)d_in[2];
    const float* v0 = (const float*)d_in[3];
    const float* v1 = (const float*)d_in[4];
    const float* v2 = (const float*)d_in[5];
    float* out = (float*)d_out;

    unsigned* mm = (unsigned*)d_ws;
    const size_t FEAT_ELEMS = (size_t)NCH * WS_P;
    float* t0 = (float*)((char*)d_ws + 256);
    float* t1 = t0 + FEAT_ELEMS;
    float* t2 = t1 + FEAT_ELEMS;
    const bool tr = ws_size >= 256 + 3 * FEAT_ELEMS * sizeof(float);

    hipLaunchKernelGGL(init_mm_kernel, dim3(1), dim3(32), 0, stream, mm);
    hipLaunchKernelGGL(minmax_kernel, dim3(128, 3), dim3(256), 0, stream,
                       v0, v1, v2, mm);

    if (tr) {
        hipLaunchKernelGGL(transpose_kernel, dim3(WS_P / 32, 3), dim3(32, 8), 0,
                           stream, f0, f1, f2, t0, t1, t2);
        hipLaunchKernelGGL((sample8_kernel<0>), dim3(WS_P / 32), dim3(256), 0,
                           stream, t0, t1, t2, v0, v1, v2, mm, out);
        hipLaunchKernelGGL((sample8_kernel<1>), dim3(WS_P / 32), dim3(256), 0,
                           stream, t0, t1, t2, v0, v1, v2, mm, out);
        hipLaunchKernelGGL((sample8_kernel<2>), dim3(WS_P / 32), dim3(256), 0,
                           stream, t0, t1, t2, v0, v1, v2, mm, out);
    } else {
        hipLaunchKernelGGL((sample_fallback_kernel<0>), dim3(WS_P / 256), dim3(256), 0,
                           stream, f0, f1, f2, v0, v1, v2, mm, out);
        hipLaunchKernelGGL((sample_fallback_kernel<1>), dim3(WS_P / 256), dim3(256), 0,
                           stream, f0, f1, f2, v0, v1, v2, mm, out);
        hipLaunchKernelGGL((sample_fallback_kernel<2>), dim3(WS_P / 256), dim3(256), 0,
                           stream, f0, f1, f2, v0, v1, v2, mm, out);
    }
}

// Round 3
// 622.388 us; speedup vs baseline: 1.6494x; 1.0098x over previous
//
#include <hip/hip_runtime.h>

// Shapes: feat0 [32,128,128,32], feat1 [32,128,32,128], feat2 [32,32,128,128]
// P = 524288 points per grid; out [3,32,P] fp32.

#define WS_P 524288
#define NCH 32

typedef float v4f __attribute__((ext_vector_type(4)));

__device__ __forceinline__ float ntloadf(const float* p) {
    return __builtin_nontemporal_load(p);
}
__device__ __forceinline__ void ntstoref(float* p, float v) {
    __builtin_nontemporal_store(v, p);
}

// ---- ordered-uint encoding for float atomic min/max (exact, order-independent)
__device__ __forceinline__ unsigned encf(float f) {
    unsigned b = __float_as_uint(f);
    return (b & 0x80000000u) ? ~b : (b | 0x80000000u);
}
__device__ __forceinline__ float decf(unsigned u) {
    unsigned b = (u & 0x80000000u) ? (u & 0x7FFFFFFFu) : ~u;
    return __uint_as_float(b);
}

__global__ void init_mm_kernel(unsigned* mm) {
    int t = threadIdx.x;
    if (t < 18) mm[t] = (t & 1) ? 0u : 0xFFFFFFFFu;
}

__global__ __launch_bounds__(256) void minmax_kernel(
    const float* __restrict__ v0, const float* __restrict__ v1,
    const float* __restrict__ v2, unsigned* __restrict__ mm)
{
    const int g = blockIdx.y;
    const float* v = (g == 0) ? v0 : (g == 1) ? v1 : v2;
    const int tid = threadIdx.x;

    float mn[3] = { INFINITY, INFINITY, INFINITY };
    float mx[3] = { -INFINITY, -INFINITY, -INFINITY };

    for (int idx = blockIdx.x * 256 + tid; idx < WS_P; idx += 128 * 256) {
        #pragma unroll
        for (int k = 0; k < 3; k++) {
            float f = ntloadf(&v[(size_t)idx * 3 + k]);
            mn[k] = fminf(mn[k], f);
            mx[k] = fmaxf(mx[k], f);
        }
    }

    __shared__ float smn[3][256];
    __shared__ float smx[3][256];
    #pragma unroll
    for (int k = 0; k < 3; k++) { smn[k][tid] = mn[k]; smx[k][tid] = mx[k]; }
    __syncthreads();

    for (int s = 128; s > 0; s >>= 1) {
        if (tid < s) {
            #pragma unroll
            for (int k = 0; k < 3; k++) {
                smn[k][tid] = fminf(smn[k][tid], smn[k][tid + s]);
                smx[k][tid] = fmaxf(smx[k][tid], smx[k][tid + s]);
            }
        }
        __syncthreads();
    }

    if (tid == 0) {
        #pragma unroll
        for (int k = 0; k < 3; k++) {
            atomicMin(&mm[g * 6 + k * 2 + 0], encf(smn[k][0]));
            atomicMax(&mm[g * 6 + k * 2 + 1], encf(smx[k][0]));
        }
    }
}

// [C][N] -> [N][C] transpose, 32x32 tiles via LDS. blockIdx.y selects feat.
// Input reads are non-temporal (re-read later via store-phase add); output
// (the gather source) allocates normally so it stays L3-resident.
__global__ __launch_bounds__(256) void transpose_kernel(
    const float* __restrict__ f0, const float* __restrict__ f1,
    const float* __restrict__ f2,
    float* __restrict__ t0, float* __restrict__ t1, float* __restrict__ t2)
{
    const int j = blockIdx.y;
    const float* in = (j == 0) ? f0 : (j == 1) ? f1 : f2;
    float* out = (j == 0) ? t0 : (j == 1) ? t1 : t2;

    __shared__ float tile[32][33];
    const int tx = threadIdx.x;   // 0..31
    const int ty = threadIdx.y;   // 0..7
    const int n0 = blockIdx.x * 32;

    #pragma unroll
    for (int r = 0; r < 4; r++) {
        int c = ty + r * 8;
        tile[c][tx] = ntloadf(&in[(size_t)c * WS_P + n0 + tx]);
    }
    __syncthreads();
    #pragma unroll
    for (int r = 0; r < 4; r++) {
        int pl = ty + r * 8;
        out[(size_t)(n0 + pl) * NCH + tx] = tile[tx][pl];
    }
}

// 8 lanes per point; each lane owns 4 channels (one float4 of the 128 B
// channel row). Gathers cached (L3-resident ti); all streams non-temporal.
template<int I>
__device__ __forceinline__ void sample_body(
    const float* __restrict__ f0, const float* __restrict__ f1,
    const float* __restrict__ f2,
    const float* __restrict__ t0, const float* __restrict__ t1,
    const float* __restrict__ t2,
    const float* __restrict__ v0, const float* __restrict__ v1,
    const float* __restrict__ v2,
    const unsigned* __restrict__ mm, float* __restrict__ out)
{
    constexpr int Dd[3] = { 128, 128, 32 };
    constexpr int Hh[3] = { 128, 32, 128 };
    constexpr int Ww[3] = { 32, 128, 128 };

    const int tid = threadIdx.x;
    const int p = blockIdx.x * 32 + (tid >> 3);   // point index
    const int subp = tid & 7;                     // which float4 of 32 channels

    const float* verts = (I == 0) ? v0 : (I == 1) ? v1 : v2;
    const float* fi    = (I == 0) ? f0 : (I == 1) ? f1 : f2;

    float g[3];
    #pragma unroll
    for (int k = 0; k < 3; k++) {
        float mn = decf(mm[I * 6 + k * 2 + 0]);
        float mx = decf(mm[I * 6 + k * 2 + 1]);
        float vv = ntloadf(&verts[(size_t)p * 3 + k]);
        g[k] = (vv - mn) / (mx - mn) * 2.0f - 1.0f;
    }

    float4 acc = make_float4(0.f, 0.f, 0.f, 0.f);

    #pragma unroll
    for (int jj = 0; jj < 2; jj++) {
        const int j = (I + 1 + jj) % 3;   // compile-time after unroll
        const float* src = (j == 0) ? t0 : (j == 1) ? t1 : t2;
        const int W = Ww[j], H = Hh[j], D = Dd[j];

        float ix = (g[0] + 1.0f) * 0.5f * (float)(W - 1);
        float iy = (g[1] + 1.0f) * 0.5f * (float)(H - 1);
        float iz = (g[2] + 1.0f) * 0.5f * (float)(D - 1);
        float fx = floorf(ix), fy = floorf(iy), fz = floorf(iz);
        float wx = ix - fx, wy = iy - fy, wz = iz - fz;

        int x0 = (int)fx; x0 = x0 < 0 ? 0 : (x0 > W - 1 ? W - 1 : x0);
        int y0 = (int)fy; y0 = y0 < 0 ? 0 : (y0 > H - 1 ? H - 1 : y0);
        int z0 = (int)fz; z0 = z0 < 0 ? 0 : (z0 > D - 1 ? D - 1 : z0);
        int x1 = (x0 + 1 > W - 1) ? W - 1 : x0 + 1;
        int y1 = (y0 + 1 > H - 1) ? H - 1 : y0 + 1;
        int z1 = (z0 + 1 > D - 1) ? D - 1 : z0 + 1;

        float ux = 1.0f - wx, uy = 1.0f - wy, uz = 1.0f - wz;
        float w[8] = { uz * uy * ux, uz * uy * wx, uz * wy * ux, uz * wy * wx,
                       wz * uy * ux, wz * uy * wx, wz * wy * ux, wz * wy * wx };

        int r00 = (z0 * H + y0) * W;
        int r01 = (z0 * H + y1) * W;
        int r10 = (z1 * H + y0) * W;
        int r11 = (z1 * H + y1) * W;
        int o[8] = { r00 + x0, r00 + x1, r01 + x0, r01 + x1,
                     r10 + x0, r10 + x1, r11 + x0, r11 + x1 };

        const float4* s4 = reinterpret_cast<const float4*>(src);
        #pragma unroll
        for (int h = 0; h < 2; h++) {
            float4 fA = s4[(size_t)o[h * 4 + 0] * 8 + subp];
            float4 fB = s4[(size_t)o[h * 4 + 1] * 8 + subp];
            float4 fC = s4[(size_t)o[h * 4 + 2] * 8 + subp];
            float4 fD = s4[(size_t)o[h * 4 + 3] * 8 + subp];
            float wA = w[h * 4 + 0], wB = w[h * 4 + 1];
            float wC = w[h * 4 + 2], wD = w[h * 4 + 3];
            acc.x = fmaf(wA, fA.x, acc.x); acc.y = fmaf(wA, fA.y, acc.y);
            acc.z = fmaf(wA, fA.z, acc.z); acc.w = fmaf(wA, fA.w, acc.w);
            acc.x = fmaf(wB, fB.x, acc.x); acc.y = fmaf(wB, fB.y, acc.y);
            acc.z = fmaf(wB, fB.z, acc.z); acc.w = fmaf(wB, fB.w, acc.w);
            acc.x = fmaf(wC, fC.x, acc.x); acc.y = fmaf(wC, fC.y, acc.y);
            acc.z = fmaf(wC, fC.z, acc.z); acc.w = fmaf(wC, fC.w, acc.w);
            acc.x = fmaf(wD, fD.x, acc.x); acc.y = fmaf(wD, fD.y, acc.y);
            acc.z = fmaf(wD, fD.z, acc.z); acc.w = fmaf(wD, fD.w, acc.w);
        }
    }

    // transpose through LDS; store phase adds feat_i from its ORIGINAL
    // layout (coalesced NT read) and stores NT — no L3 pollution.
    __shared__ float sb[32][33];
    const int pl = tid >> 3;
    sb[pl][subp * 4 + 0] = acc.x;
    sb[pl][subp * 4 + 1] = acc.y;
    sb[pl][subp * 4 + 2] = acc.z;
    sb[pl][subp * 4 + 3] = acc.w;
    __syncthreads();

    const int p0 = blockIdx.x * 32;
    float* op = out + (size_t)I * NCH * WS_P;
    #pragma unroll
    for (int it = 0; it < 4; it++) {
        int c = it * 8 + (tid >> 5);
        size_t off = (size_t)c * WS_P + p0 + (tid & 31);
        ntstoref(&op[off], sb[tid & 31][c] + ntloadf(&fi[off]));
    }
}

__global__ __launch_bounds__(256, 8) void fused_sample_kernel(
    const float* __restrict__ f0, const float* __restrict__ f1,
    const float* __restrict__ f2,
    const float* __restrict__ t0, const float* __restrict__ t1,
    const float* __restrict__ t2,
    const float* __restrict__ v0, const float* __restrict__ v1,
    const float* __restrict__ v2,
    const unsigned* __restrict__ mm, float* __restrict__ out)
{
    switch (blockIdx.y) {
        case 0: sample_body<0>(f0, f1, f2, t0, t1, t2, v0, v1, v2, mm, out); break;
        case 1: sample_body<1>(f0, f1, f2, t0, t1, t2, v0, v1, v2, mm, out); break;
        default: sample_body<2>(f0, f1, f2, t0, t1, t2, v0, v1, v2, mm, out); break;
    }
}

// fallback (ws too small): 1-thread-per-point scalar-gather from original layout
template<int I>
__global__ __launch_bounds__(256) void sample_fallback_kernel(
    const float* __restrict__ f0, const float* __restrict__ f1,
    const float* __restrict__ f2,
    const float* __restrict__ v0, const float* __restrict__ v1,
    const float* __restrict__ v2,
    const unsigned* __restrict__ mm, float* __restrict__ out)
{
    constexpr int Dd[3] = { 128, 128, 32 };
    constexpr int Hh[3] = { 128, 32, 128 };
    constexpr int Ww[3] = { 32, 128, 128 };

    const int p = blockIdx.x * 256 + threadIdx.x;
    const float* verts = (I == 0) ? v0 : (I == 1) ? v1 : v2;
    const float* fi    = (I == 0) ? f0 : (I == 1) ? f1 : f2;

    float g[3];
    #pragma unroll
    for (int k = 0; k < 3; k++) {
        float mn = decf(mm[I * 6 + k * 2 + 0]);
        float mx = decf(mm[I * 6 + k * 2 + 1]);
        float vv = verts[(size_t)p * 3 + k];
        g[k] = (vv - mn) / (mx - mn) * 2.0f - 1.0f;
    }

    float acc[NCH];
    #pragma unroll
    for (int c = 0; c < NCH; c++) acc[c] = fi[(size_t)c * WS_P + p];

    #pragma unroll
    for (int jj = 0; jj < 2; jj++) {
        const int j = (I + 1 + jj) % 3;
        const float* src = (j == 0) ? f0 : (j == 1) ? f1 : f2;
        const int W = Ww[j], H = Hh[j], D = Dd[j];

        float ix = (g[0] + 1.0f) * 0.5f * (float)(W - 1);
        float iy = (g[1] + 1.0f) * 0.5f * (float)(H - 1);
        float iz = (g[2] + 1.0f) * 0.5f * (float)(D - 1);
        float fx = floorf(ix), fy = floorf(iy), fz = floorf(iz);
        float wx = ix - fx, wy = iy - fy, wz = iz - fz;

        int x0 = (int)fx; x0 = x0 < 0 ? 0 : (x0 > W - 1 ? W - 1 : x0);
        int y0 = (int)fy; y0 = y0 < 0 ? 0 : (y0 > H - 1 ? H - 1 : y0);
        int z0 = (int)fz; z0 = z0 < 0 ? 0 : (z0 > D - 1 ? D - 1 : z0);
        int x1 = (x0 + 1 > W - 1) ? W - 1 : x0 + 1;
        int y1 = (y0 + 1 > H - 1) ? H - 1 : y0 + 1;
        int z1 = (z0 + 1 > D - 1) ? D - 1 : z0 + 1;

        float ux = 1.0f - wx, uy = 1.0f - wy, uz = 1.0f - wz;
        float w[8] = { uz * uy * ux, uz * uy * wx, uz * wy * ux, uz * wy * wx,
                       wz * uy * ux, wz * uy * wx, wz * wy * ux, wz * wy * wx };

        int r00 = (z0 * H + y0) * W;
        int r01 = (z0 * H + y1) * W;
        int r10 = (z1 * H + y0) * W;
        int r11 = (z1 * H + y1) * W;
        int o[8] = { r00 + x0, r00 + x1, r01 + x0, r01 + x1,
                     r10 + x0, r10 + x1, r11 + x0, r11 + x1 };

        #pragma unroll
        for (int cn = 0; cn < 8; cn++) {
            float wt = w[cn];
            const float* sp = src + o[cn];
            #pragma unroll
            for (int c = 0; c < NCH; c++)
                acc[c] = fmaf(wt, sp[(size_t)c * WS_P], acc[c]);
        }
    }

    float* op = out + (size_t)I * NCH * WS_P + p;
    #pragma unroll
    for (int c = 0; c < NCH; c++) op[(size_t)c * WS_P] = acc[c];
}

extern "C" void kernel_launch(void* const* d_in, const int* in_sizes, int n_in,
                              void* d_out, int out_size, void* d_ws, size_t ws_size,
                              hipStream_t stream) {
    const float* f0 = (const float*)d_in[0];
    const float* f1 = (const float*)d_in[1];
    const float* f2 = (const float*)d_in[2];
    const float* v0 = (const float*)d_in[3];
    const float* v1 = (const float*)d_in[4];
    const float* v2 = (const float*)d_in[5];
    float* out = (float*)d_out;

    unsigned* mm = (unsigned*)d_ws;
    const size_t FEAT_ELEMS = (size_t)NCH * WS_P;
    float* t0 = (float*)((char*)d_ws + 256);
    float* t1 = t0 + FEAT_ELEMS;
    float* t2 = t1 + FEAT_ELEMS;
    const bool tr = ws_size >= 256 + 3 * FEAT_ELEMS * sizeof(float);

    hipLaunchKernelGGL(init_mm_kernel, dim3(1), dim3(32), 0, stream, mm);
    hipLaunchKernelGGL(minmax_kernel, dim3(128, 3), dim3(256), 0, stream,
                       v0, v1, v2, mm);

    if (tr) {
        hipLaunchKernelGGL(transpose_kernel, dim3(WS_P / 32, 3), dim3(32, 8), 0,
                           stream, f0, f1, f2, t0, t1, t2);
        hipLaunchKernelGGL(fused_sample_kernel, dim3(WS_P / 32, 3), dim3(256), 0,
                           stream, f0, f1, f2, t0, t1, t2, v0, v1, v2, mm, out);
    } else {
        hipLaunchKernelGGL((sample_fallback_kernel<0>), dim3(WS_P / 256), dim3(256), 0,
                           stream, f0, f1, f2, v0, v1, v2, mm, out);
        hipLaunchKernelGGL((sample_fallback_kernel<1>), dim3(WS_P / 256), dim3(256), 0,
                           stream, f0, f1, f2, v0, v1, v2, mm, out);
        hipLaunchKernelGGL((sample_fallback_kernel<2>), dim3(WS_P / 256), dim3(256), 0,
                           stream, f0, f1, f2, v0, v1, v2, mm, out);
    }
}

// Round 4
// 482.071 us; speedup vs baseline: 2.1295x; 1.2911x over previous
//
#include <hip/hip_runtime.h>
#include <hip/hip_fp16.h>

// Shapes: feat0 [32,128,128,32], feat1 [32,128,32,128], feat2 [32,32,128,128]
// P = 524288 points per grid; out [3,32,P] fp32.
// Gather sources are transposed to [P][32] and stored FP16 (96 MB total,
// MALL-resident). Identity term (+feat_i) is added exactly in fp32 at the
// store phase from the original layout.

#define WS_P 524288
#define NCH 32

__device__ __forceinline__ float ntloadf(const float* p) {
    return __builtin_nontemporal_load(p);
}
__device__ __forceinline__ void ntstoref(float* p, float v) {
    __builtin_nontemporal_store(v, p);
}

// ---- ordered-uint encoding for float atomic min/max (exact, order-independent)
__device__ __forceinline__ unsigned encf(float f) {
    unsigned b = __float_as_uint(f);
    return (b & 0x80000000u) ? ~b : (b | 0x80000000u);
}
__device__ __forceinline__ float decf(unsigned u) {
    unsigned b = (u & 0x80000000u) ? (u & 0x7FFFFFFFu) : ~u;
    return __uint_as_float(b);
}

__global__ void init_mm_kernel(unsigned* mm) {
    int t = threadIdx.x;
    if (t < 18) mm[t] = (t & 1) ? 0u : 0xFFFFFFFFu;
}

__global__ __launch_bounds__(256) void minmax_kernel(
    const float* __restrict__ v0, const float* __restrict__ v1,
    const float* __restrict__ v2, unsigned* __restrict__ mm)
{
    const int g = blockIdx.y;
    const float* v = (g == 0) ? v0 : (g == 1) ? v1 : v2;
    const int tid = threadIdx.x;

    float mn[3] = { INFINITY, INFINITY, INFINITY };
    float mx[3] = { -INFINITY, -INFINITY, -INFINITY };

    for (int idx = blockIdx.x * 256 + tid; idx < WS_P; idx += 128 * 256) {
        #pragma unroll
        for (int k = 0; k < 3; k++) {
            float f = ntloadf(&v[(size_t)idx * 3 + k]);
            mn[k] = fminf(mn[k], f);
            mx[k] = fmaxf(mx[k], f);
        }
    }

    __shared__ float smn[3][256];
    __shared__ float smx[3][256];
    #pragma unroll
    for (int k = 0; k < 3; k++) { smn[k][tid] = mn[k]; smx[k][tid] = mx[k]; }
    __syncthreads();

    for (int s = 128; s > 0; s >>= 1) {
        if (tid < s) {
            #pragma unroll
            for (int k = 0; k < 3; k++) {
                smn[k][tid] = fminf(smn[k][tid], smn[k][tid + s]);
                smx[k][tid] = fmaxf(smx[k][tid], smx[k][tid + s]);
            }
        }
        __syncthreads();
    }

    if (tid == 0) {
        #pragma unroll
        for (int k = 0; k < 3; k++) {
            atomicMin(&mm[g * 6 + k * 2 + 0], encf(smn[k][0]));
            atomicMax(&mm[g * 6 + k * 2 + 1], encf(smx[k][0]));
        }
    }
}

// [C][N] fp32 -> [N][C] fp16 transpose, 32x32 tiles via LDS.
__global__ __launch_bounds__(256) void transpose16_kernel(
    const float* __restrict__ f0, const float* __restrict__ f1,
    const float* __restrict__ f2,
    __half* __restrict__ t0, __half* __restrict__ t1, __half* __restrict__ t2)
{
    const int j = blockIdx.y;
    const float* in = (j == 0) ? f0 : (j == 1) ? f1 : f2;
    __half* out = (j == 0) ? t0 : (j == 1) ? t1 : t2;

    __shared__ float tile[32][33];
    const int tx = threadIdx.x;   // 0..31
    const int ty = threadIdx.y;   // 0..7
    const int n0 = blockIdx.x * 32;

    #pragma unroll
    for (int r = 0; r < 4; r++) {
        int c = ty + r * 8;
        tile[c][tx] = ntloadf(&in[(size_t)c * WS_P + n0 + tx]);
    }
    __syncthreads();

    // write phase: 512 half2 per tile; lane mapping cp = tid&15 (consecutive
    // 4B addresses), pl = 2 rows per iteration pair
    __half2* out2 = reinterpret_cast<__half2*>(out);
    const int tid = ty * 32 + tx;
    const int cp = tid & 15;           // channel pair 0..15
    #pragma unroll
    for (int r = 0; r < 2; r++) {
        int pl = (tid >> 4) + r * 16;  // point-in-tile 0..31
        float a = tile[cp * 2 + 0][pl];
        float b = tile[cp * 2 + 1][pl];
        out2[(size_t)(n0 + pl) * 16 + cp] = __floats2half2_rn(a, b);
    }
}

// 8 lanes per point; each lane owns 4 channels (8 B of the 64 B fp16
// channel row). Gathers cached; all streaming traffic non-temporal.
template<int I>
__device__ __forceinline__ void sample_body(
    const float* __restrict__ f0, const float* __restrict__ f1,
    const float* __restrict__ f2,
    const __half* __restrict__ t0, const __half* __restrict__ t1,
    const __half* __restrict__ t2,
    const float* __restrict__ v0, const float* __restrict__ v1,
    const float* __restrict__ v2,
    const unsigned* __restrict__ mm, float* __restrict__ out,
    float (*sb)[33])
{
    constexpr int Dd[3] = { 128, 128, 32 };
    constexpr int Hh[3] = { 128, 32, 128 };
    constexpr int Ww[3] = { 32, 128, 128 };

    const int tid = threadIdx.x;
    const int p = blockIdx.x * 32 + (tid >> 3);   // point index
    const int subp = tid & 7;                     // which 4-channel group

    const float* verts = (I == 0) ? v0 : (I == 1) ? v1 : v2;
    const float* fi    = (I == 0) ? f0 : (I == 1) ? f1 : f2;

    float g[3];
    #pragma unroll
    for (int k = 0; k < 3; k++) {
        float mn = decf(mm[I * 6 + k * 2 + 0]);
        float mx = decf(mm[I * 6 + k * 2 + 1]);
        float vv = ntloadf(&verts[(size_t)p * 3 + k]);
        g[k] = (vv - mn) / (mx - mn) * 2.0f - 1.0f;
    }

    float4 acc = make_float4(0.f, 0.f, 0.f, 0.f);

    #pragma unroll
    for (int jj = 0; jj < 2; jj++) {
        const int j = (I + 1 + jj) % 3;   // compile-time after unroll
        const __half* src = (j == 0) ? t0 : (j == 1) ? t1 : t2;
        const int W = Ww[j], H = Hh[j], D = Dd[j];

        float ix = (g[0] + 1.0f) * 0.5f * (float)(W - 1);
        float iy = (g[1] + 1.0f) * 0.5f * (float)(H - 1);
        float iz = (g[2] + 1.0f) * 0.5f * (float)(D - 1);
        float fx = floorf(ix), fy = floorf(iy), fz = floorf(iz);
        float wx = ix - fx, wy = iy - fy, wz = iz - fz;

        int x0 = (int)fx; x0 = x0 < 0 ? 0 : (x0 > W - 1 ? W - 1 : x0);
        int y0 = (int)fy; y0 = y0 < 0 ? 0 : (y0 > H - 1 ? H - 1 : y0);
        int z0 = (int)fz; z0 = z0 < 0 ? 0 : (z0 > D - 1 ? D - 1 : z0);
        int x1 = (x0 + 1 > W - 1) ? W - 1 : x0 + 1;
        int y1 = (y0 + 1 > H - 1) ? H - 1 : y0 + 1;
        int z1 = (z0 + 1 > D - 1) ? D - 1 : z0 + 1;

        float ux = 1.0f - wx, uy = 1.0f - wy, uz = 1.0f - wz;
        float w[8] = { uz * uy * ux, uz * uy * wx, uz * wy * ux, uz * wy * wx,
                       wz * uy * ux, wz * uy * wx, wz * wy * ux, wz * wy * wx };

        int r00 = (z0 * H + y0) * W;
        int r01 = (z0 * H + y1) * W;
        int r10 = (z1 * H + y0) * W;
        int r11 = (z1 * H + y1) * W;
        int o[8] = { r00 + x0, r00 + x1, r01 + x0, r01 + x1,
                     r10 + x0, r10 + x1, r11 + x0, r11 + x1 };

        // each point-row = 32 halves = 8 uint2; lane reads uint2 (4 halves)
        const uint2* s8 = reinterpret_cast<const uint2*>(src);
        #pragma unroll
        for (int h = 0; h < 2; h++) {
            uint2 rA = s8[(size_t)o[h * 4 + 0] * 8 + subp];
            uint2 rB = s8[(size_t)o[h * 4 + 1] * 8 + subp];
            uint2 rC = s8[(size_t)o[h * 4 + 2] * 8 + subp];
            uint2 rD = s8[(size_t)o[h * 4 + 3] * 8 + subp];
            float wA = w[h * 4 + 0], wB = w[h * 4 + 1];
            float wC = w[h * 4 + 2], wD = w[h * 4 + 3];
            float2 a0 = __half22float2(*reinterpret_cast<__half2*>(&rA.x));
            float2 a1 = __half22float2(*reinterpret_cast<__half2*>(&rA.y));
            float2 b0 = __half22float2(*reinterpret_cast<__half2*>(&rB.x));
            float2 b1 = __half22float2(*reinterpret_cast<__half2*>(&rB.y));
            float2 c0 = __half22float2(*reinterpret_cast<__half2*>(&rC.x));
            float2 c1 = __half22float2(*reinterpret_cast<__half2*>(&rC.y));
            float2 d0 = __half22float2(*reinterpret_cast<__half2*>(&rD.x));
            float2 d1 = __half22float2(*reinterpret_cast<__half2*>(&rD.y));
            acc.x = fmaf(wA, a0.x, acc.x); acc.y = fmaf(wA, a0.y, acc.y);
            acc.z = fmaf(wA, a1.x, acc.z); acc.w = fmaf(wA, a1.y, acc.w);
            acc.x = fmaf(wB, b0.x, acc.x); acc.y = fmaf(wB, b0.y, acc.y);
            acc.z = fmaf(wB, b1.x, acc.z); acc.w = fmaf(wB, b1.y, acc.w);
            acc.x = fmaf(wC, c0.x, acc.x); acc.y = fmaf(wC, c0.y, acc.y);
            acc.z = fmaf(wC, c1.x, acc.z); acc.w = fmaf(wC, c1.y, acc.w);
            acc.x = fmaf(wD, d0.x, acc.x); acc.y = fmaf(wD, d0.y, acc.y);
            acc.z = fmaf(wD, d1.x, acc.z); acc.w = fmaf(wD, d1.y, acc.w);
        }
    }

    // transpose through LDS; store phase adds feat_i from its ORIGINAL
    // layout (coalesced NT read) and stores NT.
    const int pl = tid >> 3;
    sb[pl][subp * 4 + 0] = acc.x;
    sb[pl][subp * 4 + 1] = acc.y;
    sb[pl][subp * 4 + 2] = acc.z;
    sb[pl][subp * 4 + 3] = acc.w;
    __syncthreads();

    const int p0 = blockIdx.x * 32;
    float* op = out + (size_t)I * NCH * WS_P;
    #pragma unroll
    for (int it = 0; it < 4; it++) {
        int c = it * 8 + (tid >> 5);
        size_t off = (size_t)c * WS_P + p0 + (tid & 31);
        ntstoref(&op[off], sb[tid & 31][c] + ntloadf(&fi[off]));
    }
}

__global__ __launch_bounds__(256, 8) void fused_sample_kernel(
    const float* __restrict__ f0, const float* __restrict__ f1,
    const float* __restrict__ f2,
    const __half* __restrict__ t0, const __half* __restrict__ t1,
    const __half* __restrict__ t2,
    const float* __restrict__ v0, const float* __restrict__ v1,
    const float* __restrict__ v2,
    const unsigned* __restrict__ mm, float* __restrict__ out)
{
    __shared__ float sb[32][33];
    switch (blockIdx.y) {
        case 0: sample_body<0>(f0, f1, f2, t0, t1, t2, v0, v1, v2, mm, out, sb); break;
        case 1: sample_body<1>(f0, f1, f2, t0, t1, t2, v0, v1, v2, mm, out, sb); break;
        default: sample_body<2>(f0, f1, f2, t0, t1, t2, v0, v1, v2, mm, out, sb); break;
    }
}

// fallback (ws too small): 1-thread-per-point scalar-gather from original layout
template<int I>
__global__ __launch_bounds__(256) void sample_fallback_kernel(
    const float* __restrict__ f0, const float* __restrict__ f1,
    const float* __restrict__ f2,
    const float* __restrict__ v0, const float* __restrict__ v1,
    const float* __restrict__ v2,
    const unsigned* __restrict__ mm, float* __restrict__ out)
{
    constexpr int Dd[3] = { 128, 128, 32 };
    constexpr int Hh[3] = { 128, 32, 128 };
    constexpr int Ww[3] = { 32, 128, 128 };

    const int p = blockIdx.x * 256 + threadIdx.x;
    const float* verts = (I == 0) ? v0 : (I == 1) ? v1 : v2;
    const float* fi    = (I == 0) ? f0 : (I == 1) ? f1 : f2;

    float g[3];
    #pragma unroll
    for (int k = 0; k < 3; k++) {
        float mn = decf(mm[I * 6 + k * 2 + 0]);
        float mx = decf(mm[I * 6 + k * 2 + 1]);
        float vv = verts[(size_t)p * 3 + k];
        g[k] = (vv - mn) / (mx - mn) * 2.0f - 1.0f;
    }

    float acc[NCH];
    #pragma unroll
    for (int c = 0; c < NCH; c++) acc[c] = fi[(size_t)c * WS_P + p];

    #pragma unroll
    for (int jj = 0; jj < 2; jj++) {
        const int j = (I + 1 + jj) % 3;
        const float* src = (j == 0) ? f0 : (j == 1) ? f1 : f2;
        const int W = Ww[j], H = Hh[j], D = Dd[j];

        float ix = (g[0] + 1.0f) * 0.5f * (float)(W - 1);
        float iy = (g[1] + 1.0f) * 0.5f * (float)(H - 1);
        float iz = (g[2] + 1.0f) * 0.5f * (float)(D - 1);
        float fx = floorf(ix), fy = floorf(iy), fz = floorf(iz);
        float wx = ix - fx, wy = iy - fy, wz = iz - fz;

        int x0 = (int)fx; x0 = x0 < 0 ? 0 : (x0 > W - 1 ? W - 1 : x0);
        int y0 = (int)fy; y0 = y0 < 0 ? 0 : (y0 > H - 1 ? H - 1 : y0);
        int z0 = (int)fz; z0 = z0 < 0 ? 0 : (z0 > D - 1 ? D - 1 : z0);
        int x1 = (x0 + 1 > W - 1) ? W - 1 : x0 + 1;
        int y1 = (y0 + 1 > H - 1) ? H - 1 : y0 + 1;
        int z1 = (z0 + 1 > D - 1) ? D - 1 : z0 + 1;

        float ux = 1.0f - wx, uy = 1.0f - wy, uz = 1.0f - wz;
        float w[8] = { uz * uy * ux, uz * uy * wx, uz * wy * ux, uz * wy * wx,
                       wz * uy * ux, wz * uy * wx, wz * wy * ux, wz * wy * wx };

        int r00 = (z0 * H + y0) * W;
        int r01 = (z0 * H + y1) * W;
        int r10 = (z1 * H + y0) * W;
        int r11 = (z1 * H + y1) * W;
        int o[8] = { r00 + x0, r00 + x1, r01 + x0, r01 + x1,
                     r10 + x0, r10 + x1, r11 + x0, r11 + x1 };

        #pragma unroll
        for (int cn = 0; cn < 8; cn++) {
            float wt = w[cn];
            const float* sp = src + o[cn];
            #pragma unroll
            for (int c = 0; c < NCH; c++)
                acc[c] = fmaf(wt, sp[(size_t)c * WS_P], acc[c]);
        }
    }

    float* op = out + (size_t)I * NCH * WS_P + p;
    #pragma unroll
    for (int c = 0; c < NCH; c++) op[(size_t)c * WS_P] = acc[c];
}

extern "C" void kernel_launch(void* const* d_in, const int* in_sizes, int n_in,
                              void* d_out, int out_size, void* d_ws, size_t ws_size,
                              hipStream_t stream) {
    const float* f0 = (const float*)d_in[0];
    const float* f1 = (const float*)d_in[1];
    const float* f2 = (const float*)d_in[2];
    const float* v0 = (const float*)d_in[3];
    const float* v1 = (const float*)d_in[4];
    const float* v2 = (const float*)d_in[5];
    float* out = (float*)d_out;

    unsigned* mm = (unsigned*)d_ws;
    const size_t FEAT_ELEMS = (size_t)NCH * WS_P;
    __half* t0 = (__half*)((char*)d_ws + 256);
    __half* t1 = t0 + FEAT_ELEMS;
    __half* t2 = t1 + FEAT_ELEMS;
    const bool tr = ws_size >= 256 + 3 * FEAT_ELEMS * sizeof(__half);

    hipLaunchKernelGGL(init_mm_kernel, dim3(1), dim3(32), 0, stream, mm);
    hipLaunchKernelGGL(minmax_kernel, dim3(128, 3), dim3(256), 0, stream,
                       v0, v1, v2, mm);

    if (tr) {
        hipLaunchKernelGGL(transpose16_kernel, dim3(WS_P / 32, 3), dim3(32, 8), 0,
                           stream, f0, f1, f2, t0, t1, t2);
        hipLaunchKernelGGL(fused_sample_kernel, dim3(WS_P / 32, 3), dim3(256), 0,
                           stream, f0, f1, f2, t0, t1, t2, v0, v1, v2, mm, out);
    } else {
        hipLaunchKernelGGL((sample_fallback_kernel<0>), dim3(WS_P / 256), dim3(256), 0,
                           stream, f0, f1, f2, v0, v1, v2, mm, out);
        hipLaunchKernelGGL((sample_fallback_kernel<1>), dim3(WS_P / 256), dim3(256), 0,
                           stream, f0, f1, f2, v0, v1, v2, mm, out);
        hipLaunchKernelGGL((sample_fallback_kernel<2>), dim3(WS_P / 256), dim3(256), 0,
                           stream, f0, f1, f2, v0, v1, v2, mm, out);
    }
}